// Round 1
// baseline (2590.401 us; speedup 1.0000x reference)
//
#include <hip/hip_runtime.h>
#include <hip/hip_bf16.h>
#include <math.h>

#define S_N 50000
#define E_N 20000
#define K_N 128
#define D_N 128
#define NE_N 800000
#define B_N 8192
#define L_N 3
#define GATE_TILES (NE_N / 64)

typedef __attribute__((ext_vector_type(4))) float floatx4;
typedef __attribute__((ext_vector_type(8))) short short8v;

__device__ __forceinline__ unsigned short f2bf(float x) {
  unsigned int u = __float_as_uint(x);
  u += 0x7FFFu + ((u >> 16) & 1u);
  return (unsigned short)(u >> 16);
}
__device__ __forceinline__ float sigm(float z) { return 1.0f / (1.0f + __expf(-z)); }

// ---------------- prep: bf16 W1s, |pw|^T, keT ----------------
__global__ void prep_kernel(const float* __restrict__ W1_l1, const float* __restrict__ W1_l0,
                            const float* __restrict__ pw1, const float* __restrict__ pw2,
                            const float* __restrict__ pw3, const float* __restrict__ ke,
                            unsigned short* __restrict__ w1bf1, unsigned short* __restrict__ w1bf0,
                            float* __restrict__ pw1T, float* __restrict__ pw2T,
                            float* __restrict__ pw3a, float* __restrict__ keT) {
  int i = blockIdx.x * blockDim.x + threadIdx.x;
  if (i < 32768) { w1bf1[i] = f2bf(W1_l1[i]); return; }
  i -= 32768;
  if (i < 32768) { w1bf0[i] = f2bf(W1_l0[i]); return; }
  i -= 32768;
  if (i < 32768) { int d = i >> 8, j = i & 255; pw1T[i] = fabsf(pw1[j * 128 + d]); return; }
  i -= 32768;
  if (i < 32768) { int d = i >> 7, j = i & 127; pw2T[i] = fabsf(pw2[j * 256 + d]); return; }
  i -= 32768;
  if (i < 128) { pw3a[i] = fabsf(pw3[i]); return; }
  i -= 128;
  if (i < 16384) { int d = i >> 7, k = i & 127; keT[i] = ke[k * 128 + d]; return; }
}

__global__ void zero_kernel(int* __restrict__ p, int n) {
  int i = blockIdx.x * blockDim.x + threadIdx.x;
  if (i < n) p[i] = 0;
}

__global__ void hist_kernel(const int* __restrict__ u1, const int* __restrict__ i1,
                            const int* __restrict__ u0, const int* __restrict__ i0,
                            int* __restrict__ c0, int* __restrict__ c1,
                            int* __restrict__ c2, int* __restrict__ c3) {
  int e = blockIdx.x * blockDim.x + threadIdx.x;
  if (e >= NE_N) return;
  atomicAdd(&c0[u1[e]], 1);
  atomicAdd(&c1[i1[e]], 1);
  atomicAdd(&c2[u0[e]], 1);
  atomicAdd(&c3[i0[e]], 1);
}

__global__ __launch_bounds__(1024) void scan4_kernel(
    int* cA, int* rA, int* uA, int nA, int* cB, int* rB, int* uB, int nB,
    int* cC, int* rC, int* uC, int nC, int* cD, int* rD, int* uD, int nD) {
  int *c, *r, *u; int n;
  if (blockIdx.x == 0)      { c = cA; r = rA; u = uA; n = nA; }
  else if (blockIdx.x == 1) { c = cB; r = rB; u = uB; n = nB; }
  else if (blockIdx.x == 2) { c = cC; r = rC; u = uC; n = nC; }
  else                      { c = cD; r = rD; u = uD; n = nD; }
  __shared__ int tmp[1024];
  __shared__ int carry_s;
  int t = threadIdx.x;
  if (t == 0) carry_s = 0;
  __syncthreads();
  for (int base = 0; base < n; base += 1024) {
    int i = base + t;
    int v = (i < n) ? c[i] : 0;
    tmp[t] = v;
    __syncthreads();
    for (int off = 1; off < 1024; off <<= 1) {
      int y = 0;
      if (t >= off) y = tmp[t - off];
      __syncthreads();
      if (t >= off) tmp[t] += y;
      __syncthreads();
    }
    int incl = tmp[t];
    int carry = carry_s;
    if (i < n) { int ex = carry + incl - v; r[i] = ex; u[i] = ex; }
    __syncthreads();
    if (t == 1023) carry_s = carry + incl;
    __syncthreads();
  }
  if (t == 0) r[n] = carry_s;
}

__global__ void scatter_kernel(const int* __restrict__ u1, const int* __restrict__ i1,
                               const int* __restrict__ u0, const int* __restrict__ i0,
                               int* q0, int* q1, int* q2, int* q3,
                               int* __restrict__ o0, int* __restrict__ o1,
                               int* __restrict__ o2, int* __restrict__ o3) {
  int e = blockIdx.x * blockDim.x + threadIdx.x;
  if (e >= NE_N) return;
  o0[atomicAdd(&q0[u1[e]], 1)] = e;
  o1[atomicAdd(&q1[i1[e]], 1)] = e;
  o2[atomicAdd(&q2[u0[e]], 1)] = e;
  o3[atomicAdd(&q3[i0[e]], 1)] = e;
}

__global__ void init_copy(const float* __restrict__ se, const float* __restrict__ ee,
                          float* __restrict__ sA, float* __restrict__ sS,
                          float* __restrict__ eA, float* __restrict__ eS) {
  int i = blockIdx.x * blockDim.x + threadIdx.x;
  const int nS = S_N * 32, nE = E_N * 32;
  if (i < nS) { float4 v = ((const float4*)se)[i]; ((float4*)sA)[i] = v; ((float4*)sS)[i] = v; }
  if (i < nE) { float4 v = ((const float4*)ee)[i]; ((float4*)eA)[i] = v; ((float4*)eS)[i] = v; }
}

// ---------------- edge gate: logits via MFMA bf16, then v = val*(0.3*sig+0.7) ----------------
__global__ __launch_bounds__(512, 2)
void gate_kernel(const int* __restrict__ eu, const int* __restrict__ ei,
                 const float* __restrict__ uival, const float* __restrict__ iuval,
                 const float* __restrict__ epsui, const float* __restrict__ epsiu,
                 const float* __restrict__ semb, const float* __restrict__ eemb,
                 const unsigned short* __restrict__ w1bf,
                 const float* __restrict__ b1, const float* __restrict__ w2,
                 const float* __restrict__ b2,
                 float* __restrict__ vui, float* __restrict__ viu) {
  __shared__ unsigned short Xl[64][264];  // 64 edges x 256 bf16, +8 pad (stride 528B)
  __shared__ float plds[8][16];
  int t = threadIdx.x;
  int wv = t >> 6, l = t & 63;
  int sub = l & 15, grp = l >> 4;
  int nh = wv & 1, rg = wv >> 1;

  // persistent B fragments: cols nh*64 + nt*16 + sub, k = ks*32 + grp*8
  short8v bfrag[4][8];
#pragma unroll
  for (int nt = 0; nt < 4; ++nt) {
    int col = nh * 64 + nt * 16 + sub;
#pragma unroll
    for (int ks = 0; ks < 8; ++ks)
      bfrag[nt][ks] = *(const short8v*)&w1bf[(col << 8) + ks * 32 + grp * 8];
  }
  float b1v[4], w2v[4];
#pragma unroll
  for (int nt = 0; nt < 4; ++nt) {
    int col = nh * 64 + nt * 16 + sub;
    b1v[nt] = b1[col];
    w2v[nt] = w2[col];
  }
  float b2s = b2[0];

  for (int tile = blockIdx.x; tile < GATE_TILES; tile += gridDim.x) {
    int e0 = tile * 64;
    // stage X: thread t -> edge t>>3, 32 floats of [stu|exer] row
    {
      int el = t >> 3, q = t & 7;
      int eIdx = e0 + el;
      const float* srcrow;
      int kbase;
      if (q < 4) { srcrow = semb + (size_t)eu[eIdx] * 128 + q * 32; kbase = q * 32; }
      else       { srcrow = eemb + (size_t)ei[eIdx] * 128 + (q - 4) * 32; kbase = 128 + (q - 4) * 32; }
#pragma unroll
      for (int j = 0; j < 8; ++j) {
        float4 v = ((const float4*)srcrow)[j];
        unsigned int p0 = (unsigned int)f2bf(v.x) | ((unsigned int)f2bf(v.y) << 16);
        unsigned int p1 = (unsigned int)f2bf(v.z) | ((unsigned int)f2bf(v.w) << 16);
        *(uint2*)&Xl[el][kbase + j * 4] = make_uint2(p0, p1);
      }
    }
    __syncthreads();

    floatx4 zero4 = {0.f, 0.f, 0.f, 0.f};
    floatx4 acc[4] = {zero4, zero4, zero4, zero4};
#pragma unroll
    for (int ks = 0; ks < 8; ++ks) {
      short8v a = *(const short8v*)&Xl[rg * 16 + sub][ks * 32 + grp * 8];
#pragma unroll
      for (int nt = 0; nt < 4; ++nt)
        acc[nt] = __builtin_amdgcn_mfma_f32_16x16x32_bf16(a, bfrag[nt][ks], acc[nt], 0, 0, 0);
    }
    // logit partials: p[reg] = sum_cols relu(H + b1) * w2
    float p0 = 0, p1 = 0, p2 = 0, p3 = 0;
#pragma unroll
    for (int nt = 0; nt < 4; ++nt) {
      float bb = b1v[nt], ww = w2v[nt];
      p0 += fmaxf(acc[nt][0] + bb, 0.0f) * ww;
      p1 += fmaxf(acc[nt][1] + bb, 0.0f) * ww;
      p2 += fmaxf(acc[nt][2] + bb, 0.0f) * ww;
      p3 += fmaxf(acc[nt][3] + bb, 0.0f) * ww;
    }
#pragma unroll
    for (int m = 1; m < 16; m <<= 1) {
      p0 += __shfl_xor(p0, m, 64);
      p1 += __shfl_xor(p1, m, 64);
      p2 += __shfl_xor(p2, m, 64);
      p3 += __shfl_xor(p3, m, 64);
    }
    if (sub < 4) {
      float pv = (sub == 0) ? p0 : (sub == 1) ? p1 : (sub == 2) ? p2 : p3;
      plds[wv][grp * 4 + sub] = pv;
    }
    __syncthreads();
    if (wv == 0) {
      // lane l = edge local index; row-group l>>4, row l&15; sum the two col-half waves
      float logit = plds[(l >> 4) * 2][l & 15] + plds[(l >> 4) * 2 + 1][l & 15] + b2s;
      int e = e0 + l;
      float ep = fminf(fmaxf(epsui[e], 1e-6f), 1.0f - 1e-6f);
      float g = __logf(ep) - log1pf(-ep);
      float s = 1.0f / (1.0f + __expf(-(logit + g) * 5.0f));
      vui[e] = uival[e] * (0.3f * s + 0.7f);
      ep = fminf(fmaxf(epsiu[e], 1e-6f), 1.0f - 1e-6f);
      g = __logf(ep) - log1pf(-ep);
      s = 1.0f / (1.0f + __expf(-(logit + g) * 5.0f));
      viu[e] = iuval[e] * (0.3f * s + 0.7f);
    }
    __syncthreads();
  }
}

// ---------------- spmm: dst[r] = sum_A v*src[col] + sum_B v*src[col]; sum[r] += dst[r] -------
__global__ __launch_bounds__(256)
void spmm2_kernel(const int* __restrict__ rpA, const int* __restrict__ ordA,
                  const int* __restrict__ colA, const float* __restrict__ vA,
                  const int* __restrict__ rpB, const int* __restrict__ ordB,
                  const int* __restrict__ colB, const float* __restrict__ vB,
                  const float* __restrict__ src, float* __restrict__ dst,
                  float* __restrict__ sum, int nrows) {
  int w = (blockIdx.x * 256 + threadIdx.x) >> 6;
  int l = threadIdx.x & 63;
  if (w >= nrows) return;
  float ax = 0.f, ay = 0.f;
  int s0 = rpA[w], s1 = rpA[w + 1];
  for (int e = s0; e < s1; ++e) {
    int idx = ordA[e];
    float val = vA[idx];
    const float2* srow = (const float2*)(src + (size_t)colA[idx] * 128);
    float2 xv = srow[l];
    ax = fmaf(val, xv.x, ax);
    ay = fmaf(val, xv.y, ay);
  }
  s0 = rpB[w]; s1 = rpB[w + 1];
  for (int e = s0; e < s1; ++e) {
    int idx = ordB[e];
    float val = vB[idx];
    const float2* srow = (const float2*)(src + (size_t)colB[idx] * 128);
    float2 xv = srow[l];
    ax = fmaf(val, xv.x, ax);
    ay = fmaf(val, xv.y, ay);
  }
  float2 dv; dv.x = ax; dv.y = ay;
  ((float2*)(dst + (size_t)w * 128))[l] = dv;
  float2* qrow = (float2*)(sum + (size_t)w * 128);
  float2 sv = qrow[l];
  sv.x += ax; sv.y += ay;
  qrow[l] = sv;
}

// ---------------- head 1: x = e_d*(sigmoid(stat)-sigmoid(diff))*kn ----------------
__global__ __launch_bounds__(256)
void head1_kernel(const int* __restrict__ stu_id, const int* __restrict__ exer_id,
                  const float* __restrict__ kn, const float* __restrict__ stuS,
                  const float* __restrict__ exeS, const float* __restrict__ keT,
                  const float* __restrict__ stub, const float* __restrict__ exeb,
                  const float* __restrict__ disc, float* __restrict__ xbuf) {
  __shared__ float srw[4][128], erw[4][128];
  int wv = threadIdx.x >> 6, l = threadIdx.x & 63;
  int b = blockIdx.x * 4 + wv;
  int sid = stu_id[b], eid = exer_id[b];
  float2 sv = ((const float2*)(stuS + (size_t)sid * 128))[l];
  float2 ev = ((const float2*)(exeS + (size_t)eid * 128))[l];
  srw[wv][2 * l] = sv.x * 0.25f; srw[wv][2 * l + 1] = sv.y * 0.25f;
  erw[wv][2 * l] = ev.x * 0.25f; erw[wv][2 * l + 1] = ev.y * 0.25f;
  __syncthreads();
  float s0 = 0, s1 = 0, d0 = 0, d1 = 0;
  for (int d = 0; d < 128; ++d) {
    float sd = srw[wv][d], ed = erw[wv][d];
    float ka = keT[d * 128 + l], kb = keT[d * 128 + l + 64];
    s0 = fmaf(sd, ka, s0); s1 = fmaf(sd, kb, s1);
    d0 = fmaf(ed, ka, d0); d1 = fmaf(ed, kb, d1);
  }
  float sbv = stub[sid], ebv = exeb[eid];
  float edv = sigm(disc[eid]);
  float st0 = sigm(s0 + sbv), st1 = sigm(s1 + sbv);
  float df0 = sigm(d0 + ebv), df1 = sigm(d1 + ebv);
  xbuf[(size_t)b * 128 + l]      = edv * (st0 - df0) * kn[(size_t)b * 128 + l];
  xbuf[(size_t)b * 128 + l + 64] = edv * (st1 - df1) * kn[(size_t)b * 128 + l + 64];
}

// ---------------- head 2: PosLinear MLP ----------------
__global__ __launch_bounds__(256)
void head2_kernel(const float* __restrict__ xbuf, const float* __restrict__ pw1T,
                  const float* __restrict__ pb1, const float* __restrict__ pw2T,
                  const float* __restrict__ pb2, const float* __restrict__ pw3a,
                  const float* __restrict__ pb3, float* __restrict__ out) {
  __shared__ float xs[4][128], h1s[4][256], h2s[4][128];
  int wv = threadIdx.x >> 6, l = threadIdx.x & 63;
  int b = blockIdx.x * 4 + wv;
  xs[wv][l] = xbuf[(size_t)b * 128 + l];
  xs[wv][l + 64] = xbuf[(size_t)b * 128 + l + 64];
  __syncthreads();
#pragma unroll
  for (int q = 0; q < 4; ++q) {
    int j = q * 64 + l;
    float acc = 0.f;
    for (int d = 0; d < 128; ++d) acc = fmaf(xs[wv][d], pw1T[d * 256 + j], acc);
    h1s[wv][j] = sigm(acc + pb1[j]);
  }
  __syncthreads();
#pragma unroll
  for (int q = 0; q < 2; ++q) {
    int j = q * 64 + l;
    float acc = 0.f;
    for (int d = 0; d < 256; ++d) acc = fmaf(h1s[wv][d], pw2T[d * 128 + j], acc);
    h2s[wv][j] = sigm(acc + pb2[j]);
  }
  __syncthreads();
  float p = h2s[wv][l] * pw3a[l] + h2s[wv][l + 64] * pw3a[l + 64];
#pragma unroll
  for (int m = 1; m < 64; m <<= 1) p += __shfl_xor(p, m, 64);
  if (l == 0) out[b] = sigm(p + pb3[0]);
}

extern "C" void kernel_launch(void* const* d_in, const int* in_sizes, int n_in,
                              void* d_out, int out_size, void* d_ws, size_t ws_size,
                              hipStream_t stream) {
  const int*   stu_id  = (const int*)  d_in[0];
  const int*   exer_id = (const int*)  d_in[1];
  const float* kn_emb  = (const float*)d_in[2];
  const int*   ui1_u   = (const int*)  d_in[3];
  const int*   ui1_i   = (const int*)  d_in[4];
  const float* ui1_val = (const float*)d_in[5];
  const float* iu1_val = (const float*)d_in[6];
  const float* eps_ui1 = (const float*)d_in[7];
  const float* eps_iu1 = (const float*)d_in[8];
  const int*   ui0_u   = (const int*)  d_in[9];
  const int*   ui0_i   = (const int*)  d_in[10];
  const float* ui0_val = (const float*)d_in[11];
  const float* iu0_val = (const float*)d_in[12];
  const float* eps_ui0 = (const float*)d_in[13];
  const float* eps_iu0 = (const float*)d_in[14];
  const float* stu_emb = (const float*)d_in[15];
  const float* exe_emb = (const float*)d_in[16];
  const float* kno_emb = (const float*)d_in[17];
  const float* stu_b   = (const float*)d_in[18];
  const float* exe_b   = (const float*)d_in[19];
  const float* disc    = (const float*)d_in[20];
  const float* W1_l1   = (const float*)d_in[21];
  const float* b1_l1   = (const float*)d_in[22];
  const float* W2_l1   = (const float*)d_in[23];
  const float* b2_l1   = (const float*)d_in[24];
  const float* W1_l0   = (const float*)d_in[25];
  const float* b1_l0   = (const float*)d_in[26];
  const float* W2_l0   = (const float*)d_in[27];
  const float* b2_l0   = (const float*)d_in[28];
  const float* pw1     = (const float*)d_in[29];
  const float* pb1     = (const float*)d_in[30];
  const float* pw2     = (const float*)d_in[31];
  const float* pb2     = (const float*)d_in[32];
  const float* pw3     = (const float*)d_in[33];
  const float* pb3     = (const float*)d_in[34];
  float* out = (float*)d_out;
  (void)in_sizes; (void)n_in; (void)out_size; (void)ws_size;

  size_t off = 0;
  char* base = (char*)d_ws;
  auto carve = [&](size_t bytes) -> char* {
    char* p = base + off;
    off += (bytes + 255) & ~(size_t)255;
    return p;
  };
  unsigned short* w1bf1 = (unsigned short*)carve(32768 * 2);
  unsigned short* w1bf0 = (unsigned short*)carve(32768 * 2);
  float* pw1T = (float*)carve(32768 * 4);
  float* pw2T = (float*)carve(32768 * 4);
  float* pw3a = (float*)carve(128 * 4);
  float* keT  = (float*)carve(16384 * 4);
  float* v_ui1 = (float*)carve((size_t)NE_N * 4);
  float* v_iu1 = (float*)carve((size_t)NE_N * 4);
  float* v_ui0 = (float*)carve((size_t)NE_N * 4);
  float* v_iu0 = (float*)carve((size_t)NE_N * 4);
  float* stuA = (float*)carve((size_t)S_N * 128 * 4);
  float* stuB = (float*)carve((size_t)S_N * 128 * 4);
  float* stuS = (float*)carve((size_t)S_N * 128 * 4);
  float* exeA = (float*)carve((size_t)E_N * 128 * 4);
  float* exeB = (float*)carve((size_t)E_N * 128 * 4);
  float* exeS = (float*)carve((size_t)E_N * 128 * 4);
  int* c0 = (int*)carve((size_t)(S_N + E_N + S_N + E_N) * 4);
  int* c1 = c0 + S_N;
  int* c2 = c1 + E_N;
  int* c3 = c2 + S_N;
  int* r0 = (int*)carve((size_t)(S_N + 1) * 4);
  int* r1 = (int*)carve((size_t)(E_N + 1) * 4);
  int* r2 = (int*)carve((size_t)(S_N + 1) * 4);
  int* r3 = (int*)carve((size_t)(E_N + 1) * 4);
  int* q0 = (int*)carve((size_t)S_N * 4);
  int* q1 = (int*)carve((size_t)E_N * 4);
  int* q2 = (int*)carve((size_t)S_N * 4);
  int* q3 = (int*)carve((size_t)E_N * 4);
  int* o0 = (int*)carve((size_t)NE_N * 4);
  int* o1 = (int*)carve((size_t)NE_N * 4);
  int* o2 = (int*)carve((size_t)NE_N * 4);
  int* o3 = (int*)carve((size_t)NE_N * 4);
  float* xbuf = (float*)carve((size_t)B_N * 128 * 4);

  prep_kernel<<<(147584 + 255) / 256, 256, 0, stream>>>(W1_l1, W1_l0, pw1, pw2, pw3, kno_emb,
                                                        w1bf1, w1bf0, pw1T, pw2T, pw3a, keT);
  zero_kernel<<<(140000 + 255) / 256, 256, 0, stream>>>(c0, 140000);
  hist_kernel<<<NE_N / 256, 256, 0, stream>>>(ui1_u, ui1_i, ui0_u, ui0_i, c0, c1, c2, c3);
  scan4_kernel<<<4, 1024, 0, stream>>>(c0, r0, q0, S_N, c1, r1, q1, E_N,
                                       c2, r2, q2, S_N, c3, r3, q3, E_N);
  scatter_kernel<<<NE_N / 256, 256, 0, stream>>>(ui1_u, ui1_i, ui0_u, ui0_i,
                                                 q0, q1, q2, q3, o0, o1, o2, o3);
  init_copy<<<(S_N * 32 + 255) / 256, 256, 0, stream>>>(stu_emb, exe_emb, stuA, stuS, exeA, exeS);
  gate_kernel<<<1024, 512, 0, stream>>>(ui1_u, ui1_i, ui1_val, iu1_val, eps_ui1, eps_iu1,
                                        stu_emb, exe_emb, w1bf1, b1_l1, W2_l1, b2_l1,
                                        v_ui1, v_iu1);
  gate_kernel<<<1024, 512, 0, stream>>>(ui0_u, ui0_i, ui0_val, iu0_val, eps_ui0, eps_iu0,
                                        stu_emb, exe_emb, w1bf0, b1_l0, W2_l0, b2_l0,
                                        v_ui0, v_iu0);
  float* sc = stuA; float* sn = stuB; float* ec = exeA; float* en = exeB;
  for (int layer = 0; layer < L_N; ++layer) {
    spmm2_kernel<<<(S_N + 3) / 4, 256, 0, stream>>>(r0, o0, ui1_i, v_ui1, r2, o2, ui0_i, v_ui0,
                                                    ec, sn, stuS, S_N);
    spmm2_kernel<<<(E_N + 3) / 4, 256, 0, stream>>>(r1, o1, ui1_u, v_iu1, r3, o3, ui0_u, v_iu0,
                                                    sc, en, exeS, E_N);
    float* tp = sc; sc = sn; sn = tp;
    tp = ec; ec = en; en = tp;
  }
  head1_kernel<<<B_N / 4, 256, 0, stream>>>(stu_id, exer_id, kn_emb, stuS, exeS, keT,
                                            stu_b, exe_b, disc, xbuf);
  head2_kernel<<<B_N / 4, 256, 0, stream>>>(xbuf, pw1T, pb1, pw2T, pb2, pw3a, pb3, out);
}

// Round 4
// 1298.175 us; speedup vs baseline: 1.9954x; 1.9954x over previous
//
#include <hip/hip_runtime.h>
#include <hip/hip_bf16.h>
#include <math.h>

#define S_N 50000
#define E_N 20000
#define K_N 128
#define D_N 128
#define NE_N 800000
#define B_N 8192
#define L_N 3
#define GATE_TILES (NE_N / 64)

typedef __attribute__((ext_vector_type(4))) float floatx4;
typedef __attribute__((ext_vector_type(8))) short short8v;

__device__ __forceinline__ unsigned short f2bf(float x) {
  unsigned int u = __float_as_uint(x);
  u += 0x7FFFu + ((u >> 16) & 1u);
  return (unsigned short)(u >> 16);
}
__device__ __forceinline__ float bf2f(unsigned short u) {
  return __uint_as_float(((unsigned int)u) << 16);
}
__device__ __forceinline__ float sigm(float z) { return 1.0f / (1.0f + __expf(-z)); }

// ---------------- prep: bf16 W1s, |pw|^T, keT ----------------
__global__ void prep_kernel(const float* __restrict__ W1_l1, const float* __restrict__ W1_l0,
                            const float* __restrict__ pw1, const float* __restrict__ pw2,
                            const float* __restrict__ pw3, const float* __restrict__ ke,
                            unsigned short* __restrict__ w1bf1, unsigned short* __restrict__ w1bf0,
                            float* __restrict__ pw1T, float* __restrict__ pw2T,
                            float* __restrict__ pw3a, float* __restrict__ keT) {
  int i = blockIdx.x * blockDim.x + threadIdx.x;
  if (i < 32768) { w1bf1[i] = f2bf(W1_l1[i]); return; }
  i -= 32768;
  if (i < 32768) { w1bf0[i] = f2bf(W1_l0[i]); return; }
  i -= 32768;
  if (i < 32768) { int d = i >> 8, j = i & 255; pw1T[i] = fabsf(pw1[j * 128 + d]); return; }
  i -= 32768;
  if (i < 32768) { int d = i >> 7, j = i & 127; pw2T[i] = fabsf(pw2[j * 256 + d]); return; }
  i -= 32768;
  if (i < 128) { pw3a[i] = fabsf(pw3[i]); return; }
  i -= 128;
  if (i < 16384) { int d = i >> 7, k = i & 127; keT[i] = ke[k * 128 + d]; return; }
}

// ---------------- init: bf16 embedding tables + f32 sums ----------------
__global__ void init_bf_kernel(const float* __restrict__ se, const float* __restrict__ ee,
                               unsigned short* __restrict__ sbf, unsigned short* __restrict__ ebf,
                               float* __restrict__ sS, float* __restrict__ eS) {
  int i = blockIdx.x * blockDim.x + threadIdx.x;
  const int nS4 = S_N * 32, nE4 = E_N * 32;  // float4 counts
  if (i < nS4) {
    float4 v = ((const float4*)se)[i];
    ((float4*)sS)[i] = v;
    unsigned int lo = (unsigned int)f2bf(v.x) | ((unsigned int)f2bf(v.y) << 16);
    unsigned int hi = (unsigned int)f2bf(v.z) | ((unsigned int)f2bf(v.w) << 16);
    ((uint2*)sbf)[i] = make_uint2(lo, hi);
    return;
  }
  i -= nS4;
  if (i < nE4) {
    float4 v = ((const float4*)ee)[i];
    ((float4*)eS)[i] = v;
    unsigned int lo = (unsigned int)f2bf(v.x) | ((unsigned int)f2bf(v.y) << 16);
    unsigned int hi = (unsigned int)f2bf(v.z) | ((unsigned int)f2bf(v.w) << 16);
    ((uint2*)ebf)[i] = make_uint2(lo, hi);
  }
}

__global__ void zero_kernel(int* __restrict__ p, int n) {
  int i = blockIdx.x * blockDim.x + threadIdx.x;
  if (i < n) p[i] = 0;
}

// merged histogram: stu-dst counts (ui1 + ui0 rows), exe-dst counts
__global__ void hist_kernel(const int* __restrict__ u1, const int* __restrict__ i1,
                            const int* __restrict__ u0, const int* __restrict__ i0,
                            int* __restrict__ cS, int* __restrict__ cE) {
  int e = blockIdx.x * blockDim.x + threadIdx.x;
  if (e >= NE_N) return;
  atomicAdd(&cS[u1[e]], 1);
  atomicAdd(&cS[u0[e]], 1);
  atomicAdd(&cE[i1[e]], 1);
  atomicAdd(&cE[i0[e]], 1);
}

// shuffle-based exclusive scan, one block per array
__global__ __launch_bounds__(1024) void scan2_kernel(
    int* cA, int* rA, int* uA, int nA, int* cB, int* rB, int* uB, int nB) {
  int *c, *r, *u; int n;
  if (blockIdx.x == 0) { c = cA; r = rA; u = uA; n = nA; }
  else                 { c = cB; r = rB; u = uB; n = nB; }
  __shared__ int wpart[16];
  __shared__ int carry_s;
  int t = threadIdx.x, w = t >> 6, l = t & 63;
  if (t == 0) carry_s = 0;
  __syncthreads();
  for (int base = 0; base < n; base += 1024) {
    int i = base + t;
    int v = (i < n) ? c[i] : 0;
    int x = v;
#pragma unroll
    for (int off = 1; off < 64; off <<= 1) {
      int y = __shfl_up(x, off, 64);
      if (l >= off) x += y;
    }
    if (l == 63) wpart[w] = x;
    __syncthreads();
    int wo = 0, tot = 0;
#pragma unroll
    for (int j = 0; j < 16; ++j) {
      int pj = wpart[j];
      tot += pj;
      if (j < w) wo += pj;
    }
    int carry = carry_s;
    int incl = carry + wo + x;
    if (i < n) { int ex = incl - v; r[i] = ex; u[i] = ex; }
    __syncthreads();
    if (t == 0) carry_s = carry + tot;
    __syncthreads();
  }
  if (t == 0) r[n] = carry_s;
}

// scatter (col,val) pairs in CSR order
__global__ void scatter_kernel(const int* __restrict__ u1, const int* __restrict__ i1,
                               const int* __restrict__ u0, const int* __restrict__ i0,
                               const float* __restrict__ v_ui1, const float* __restrict__ v_iu1,
                               const float* __restrict__ v_ui0, const float* __restrict__ v_iu0,
                               int* qS, int* qE,
                               int2* __restrict__ pairsS, int2* __restrict__ pairsE) {
  int e = blockIdx.x * blockDim.x + threadIdx.x;
  if (e >= NE_N) return;
  int a = u1[e], b = i1[e], c = u0[e], d = i0[e];
  int p;
  p = atomicAdd(&qS[a], 1); pairsS[p] = make_int2(b, __float_as_int(v_ui1[e]));
  p = atomicAdd(&qS[c], 1); pairsS[p] = make_int2(d, __float_as_int(v_ui0[e]));
  p = atomicAdd(&qE[b], 1); pairsE[p] = make_int2(a, __float_as_int(v_iu1[e]));
  p = atomicAdd(&qE[d], 1); pairsE[p] = make_int2(c, __float_as_int(v_iu0[e]));
}

// ---------------- edge gate: logits via MFMA bf16 (bf16 tables, no conversion) ----------------
__global__ __launch_bounds__(512, 2)
void gate_kernel(const int* __restrict__ eu, const int* __restrict__ ei,
                 const float* __restrict__ uival, const float* __restrict__ iuval,
                 const float* __restrict__ epsui, const float* __restrict__ epsiu,
                 const unsigned short* __restrict__ sbf, const unsigned short* __restrict__ ebf,
                 const unsigned short* __restrict__ w1bf,
                 const float* __restrict__ b1, const float* __restrict__ w2,
                 const float* __restrict__ b2,
                 float* __restrict__ vui, float* __restrict__ viu) {
  __shared__ unsigned short Xl[64][264];  // 64 edges x 256 bf16, +8 pad
  __shared__ float plds[8][16];
  int t = threadIdx.x;
  int wv = t >> 6, l = t & 63;
  int sub = l & 15, grp = l >> 4;
  int nh = wv & 1, rg = wv >> 1;

  short8v bfrag[4][8];
#pragma unroll
  for (int nt = 0; nt < 4; ++nt) {
    int col = nh * 64 + nt * 16 + sub;
#pragma unroll
    for (int ks = 0; ks < 8; ++ks)
      bfrag[nt][ks] = *(const short8v*)&w1bf[(col << 8) + ks * 32 + grp * 8];
  }
  float b1v[4], w2v[4];
#pragma unroll
  for (int nt = 0; nt < 4; ++nt) {
    int col = nh * 64 + nt * 16 + sub;
    b1v[nt] = b1[col];
    w2v[nt] = w2[col];
  }
  float b2s = b2[0];

  for (int tile = blockIdx.x; tile < GATE_TILES; tile += gridDim.x) {
    int e0 = tile * 64;
    {  // stage: thread t -> edge t>>3, 64B chunk q of the 512B [stu|exer] bf16 row
      int el = t >> 3, q = t & 7;
      int eIdx = e0 + el;
      const unsigned short* srcrow = (q < 4)
          ? sbf + (size_t)eu[eIdx] * 128 + q * 32
          : ebf + (size_t)ei[eIdx] * 128 + (q - 4) * 32;
#pragma unroll
      for (int j = 0; j < 4; ++j)
        *(short8v*)&Xl[el][q * 32 + j * 8] = ((const short8v*)srcrow)[j];
    }
    __syncthreads();

    floatx4 zero4 = {0.f, 0.f, 0.f, 0.f};
    floatx4 acc[4] = {zero4, zero4, zero4, zero4};
#pragma unroll
    for (int ks = 0; ks < 8; ++ks) {
      short8v a = *(const short8v*)&Xl[rg * 16 + sub][ks * 32 + grp * 8];
#pragma unroll
      for (int nt = 0; nt < 4; ++nt)
        acc[nt] = __builtin_amdgcn_mfma_f32_16x16x32_bf16(a, bfrag[nt][ks], acc[nt], 0, 0, 0);
    }
    float p0 = 0, p1 = 0, p2 = 0, p3 = 0;
#pragma unroll
    for (int nt = 0; nt < 4; ++nt) {
      float bb = b1v[nt], ww = w2v[nt];
      p0 += fmaxf(acc[nt][0] + bb, 0.0f) * ww;
      p1 += fmaxf(acc[nt][1] + bb, 0.0f) * ww;
      p2 += fmaxf(acc[nt][2] + bb, 0.0f) * ww;
      p3 += fmaxf(acc[nt][3] + bb, 0.0f) * ww;
    }
#pragma unroll
    for (int m = 1; m < 16; m <<= 1) {
      p0 += __shfl_xor(p0, m, 64);
      p1 += __shfl_xor(p1, m, 64);
      p2 += __shfl_xor(p2, m, 64);
      p3 += __shfl_xor(p3, m, 64);
    }
    if (sub < 4) {
      float pv = (sub == 0) ? p0 : (sub == 1) ? p1 : (sub == 2) ? p2 : p3;
      plds[wv][grp * 4 + sub] = pv;
    }
    __syncthreads();
    if (wv == 0) {
      float logit = plds[(l >> 4) * 2][l & 15] + plds[(l >> 4) * 2 + 1][l & 15] + b2s;
      int e = e0 + l;
      float ep = fminf(fmaxf(epsui[e], 1e-6f), 1.0f - 1e-6f);
      float g = __logf(ep) - log1pf(-ep);
      float s = 1.0f / (1.0f + __expf(-(logit + g) * 5.0f));
      vui[e] = uival[e] * (0.3f * s + 0.7f);
      ep = fminf(fmaxf(epsiu[e], 1e-6f), 1.0f - 1e-6f);
      g = __logf(ep) - log1pf(-ep);
      s = 1.0f / (1.0f + __expf(-(logit + g) * 5.0f));
      viu[e] = iuval[e] * (0.3f * s + 0.7f);
    }
    __syncthreads();
  }
}

// ---------------- fused spmm: wave per dst row (stu rows then exe rows), bf16 src/dst ---------
__global__ __launch_bounds__(256)
void spmm_kernel(const int* __restrict__ rpS, const int2* __restrict__ pairsS,
                 const int* __restrict__ rpE, const int2* __restrict__ pairsE,
                 const unsigned short* __restrict__ scur, const unsigned short* __restrict__ ecur,
                 unsigned short* __restrict__ snxt, unsigned short* __restrict__ enxt,
                 float* __restrict__ stuS, float* __restrict__ exeS) {
  int w = (blockIdx.x * 256 + threadIdx.x) >> 6;
  int l = threadIdx.x & 63;
  int sub = l & 15, eg = l >> 4;
  const int* rp; const int2* pairs; const unsigned short* src;
  unsigned short* dst; float* sum; int r;
  if (w < S_N) { r = w;       rp = rpS; pairs = pairsS; src = ecur; dst = snxt; sum = stuS; }
  else         { r = w - S_N; rp = rpE; pairs = pairsE; src = scur; dst = enxt; sum = exeS; }
  float acc[8] = {0.f, 0.f, 0.f, 0.f, 0.f, 0.f, 0.f, 0.f};
  int s0 = rp[r], s1 = rp[r + 1];
  for (int e = s0; e < s1; e += 4) {
    int ee = e + eg;
    int2 p = (ee < s1) ? pairs[ee] : make_int2(0, 0);
    float val = __int_as_float(p.y);
    short8v xv = *(const short8v*)(src + (size_t)p.x * 128 + sub * 8);
#pragma unroll
    for (int j = 0; j < 8; ++j)
      acc[j] = fmaf(val, bf2f((unsigned short)xv[j]), acc[j]);
  }
#pragma unroll
  for (int j = 0; j < 8; ++j) {
    acc[j] += __shfl_xor(acc[j], 16, 64);
    acc[j] += __shfl_xor(acc[j], 32, 64);
  }
  if (eg == 0) {
    short8v ov;
#pragma unroll
    for (int j = 0; j < 8; ++j) ov[j] = (short)f2bf(acc[j]);
    *(short8v*)(dst + (size_t)r * 128 + sub * 8) = ov;
    float4* sp = (float4*)(sum + (size_t)r * 128 + sub * 8);
    float4 a0 = sp[0], a1 = sp[1];
    a0.x += acc[0]; a0.y += acc[1]; a0.z += acc[2]; a0.w += acc[3];
    a1.x += acc[4]; a1.y += acc[5]; a1.z += acc[6]; a1.w += acc[7];
    sp[0] = a0; sp[1] = a1;
  }
}

// ---------------- head 1 ----------------
__global__ __launch_bounds__(256)
void head1_kernel(const int* __restrict__ stu_id, const int* __restrict__ exer_id,
                  const float* __restrict__ kn, const float* __restrict__ stuS,
                  const float* __restrict__ exeS, const float* __restrict__ keT,
                  const float* __restrict__ stub, const float* __restrict__ exeb,
                  const float* __restrict__ disc, float* __restrict__ xbuf) {
  __shared__ float srw[4][128], erw[4][128];
  int wv = threadIdx.x >> 6, l = threadIdx.x & 63;
  int b = blockIdx.x * 4 + wv;
  int sid = stu_id[b], eid = exer_id[b];
  float2 sv = ((const float2*)(stuS + (size_t)sid * 128))[l];
  float2 ev = ((const float2*)(exeS + (size_t)eid * 128))[l];
  srw[wv][2 * l] = sv.x * 0.25f; srw[wv][2 * l + 1] = sv.y * 0.25f;
  erw[wv][2 * l] = ev.x * 0.25f; erw[wv][2 * l + 1] = ev.y * 0.25f;
  __syncthreads();
  float s0 = 0, s1 = 0, d0 = 0, d1 = 0;
  for (int d = 0; d < 128; ++d) {
    float sd = srw[wv][d], ed = erw[wv][d];
    float ka = keT[d * 128 + l], kb = keT[d * 128 + l + 64];
    s0 = fmaf(sd, ka, s0); s1 = fmaf(sd, kb, s1);
    d0 = fmaf(ed, ka, d0); d1 = fmaf(ed, kb, d1);
  }
  float sbv = stub[sid], ebv = exeb[eid];
  float edv = sigm(disc[eid]);
  float st0 = sigm(s0 + sbv), st1 = sigm(s1 + sbv);
  float df0 = sigm(d0 + ebv), df1 = sigm(d1 + ebv);
  xbuf[(size_t)b * 128 + l]      = edv * (st0 - df0) * kn[(size_t)b * 128 + l];
  xbuf[(size_t)b * 128 + l + 64] = edv * (st1 - df1) * kn[(size_t)b * 128 + l + 64];
}

// ---------------- head 2: PosLinear MLP ----------------
__global__ __launch_bounds__(256)
void head2_kernel(const float* __restrict__ xbuf, const float* __restrict__ pw1T,
                  const float* __restrict__ pb1, const float* __restrict__ pw2T,
                  const float* __restrict__ pb2, const float* __restrict__ pw3a,
                  const float* __restrict__ pb3, float* __restrict__ out) {
  __shared__ float xs[4][128], h1s[4][256], h2s[4][128];
  int wv = threadIdx.x >> 6, l = threadIdx.x & 63;
  int b = blockIdx.x * 4 + wv;
  xs[wv][l] = xbuf[(size_t)b * 128 + l];
  xs[wv][l + 64] = xbuf[(size_t)b * 128 + l + 64];
  __syncthreads();
#pragma unroll
  for (int q = 0; q < 4; ++q) {
    int j = q * 64 + l;
    float acc = 0.f;
    for (int d = 0; d < 128; ++d) acc = fmaf(xs[wv][d], pw1T[d * 256 + j], acc);
    h1s[wv][j] = sigm(acc + pb1[j]);
  }
  __syncthreads();
#pragma unroll
  for (int q = 0; q < 2; ++q) {
    int j = q * 64 + l;
    float acc = 0.f;
    for (int d = 0; d < 256; ++d) acc = fmaf(h1s[wv][d], pw2T[d * 128 + j], acc);
    h2s[wv][j] = sigm(acc + pb2[j]);
  }
  __syncthreads();
  float p = h2s[wv][l] * pw3a[l] + h2s[wv][l + 64] * pw3a[l + 64];
#pragma unroll
  for (int m = 1; m < 64; m <<= 1) p += __shfl_xor(p, m, 64);
  if (l == 0) out[b] = sigm(p + pb3[0]);
}

extern "C" void kernel_launch(void* const* d_in, const int* in_sizes, int n_in,
                              void* d_out, int out_size, void* d_ws, size_t ws_size,
                              hipStream_t stream) {
  const int*   stu_id  = (const int*)  d_in[0];
  const int*   exer_id = (const int*)  d_in[1];
  const float* kn_emb  = (const float*)d_in[2];
  const int*   ui1_u   = (const int*)  d_in[3];
  const int*   ui1_i   = (const int*)  d_in[4];
  const float* ui1_val = (const float*)d_in[5];
  const float* iu1_val = (const float*)d_in[6];
  const float* eps_ui1 = (const float*)d_in[7];
  const float* eps_iu1 = (const float*)d_in[8];
  const int*   ui0_u   = (const int*)  d_in[9];
  const int*   ui0_i   = (const int*)  d_in[10];
  const float* ui0_val = (const float*)d_in[11];
  const float* iu0_val = (const float*)d_in[12];
  const float* eps_ui0 = (const float*)d_in[13];
  const float* eps_iu0 = (const float*)d_in[14];
  const float* stu_emb = (const float*)d_in[15];
  const float* exe_emb = (const float*)d_in[16];
  const float* kno_emb = (const float*)d_in[17];
  const float* stu_b   = (const float*)d_in[18];
  const float* exe_b   = (const float*)d_in[19];
  const float* disc    = (const float*)d_in[20];
  const float* W1_l1   = (const float*)d_in[21];
  const float* b1_l1   = (const float*)d_in[22];
  const float* W2_l1   = (const float*)d_in[23];
  const float* b2_l1   = (const float*)d_in[24];
  const float* W1_l0   = (const float*)d_in[25];
  const float* b1_l0   = (const float*)d_in[26];
  const float* W2_l0   = (const float*)d_in[27];
  const float* b2_l0   = (const float*)d_in[28];
  const float* pw1     = (const float*)d_in[29];
  const float* pb1     = (const float*)d_in[30];
  const float* pw2     = (const float*)d_in[31];
  const float* pb2     = (const float*)d_in[32];
  const float* pw3     = (const float*)d_in[33];
  const float* pb3     = (const float*)d_in[34];
  float* out = (float*)d_out;
  (void)in_sizes; (void)n_in; (void)out_size; (void)ws_size;

  size_t off = 0;
  char* base = (char*)d_ws;
  auto carve = [&](size_t bytes) -> char* {
    char* p = base + off;
    off += (bytes + 255) & ~(size_t)255;
    return p;
  };
  unsigned short* w1bf1 = (unsigned short*)carve(32768 * 2);
  unsigned short* w1bf0 = (unsigned short*)carve(32768 * 2);
  float* pw1T = (float*)carve(32768 * 4);
  float* pw2T = (float*)carve(32768 * 4);
  float* pw3a = (float*)carve(128 * 4);
  float* keT  = (float*)carve(16384 * 4);
  float* v_ui1 = (float*)carve((size_t)NE_N * 4);
  float* v_iu1 = (float*)carve((size_t)NE_N * 4);
  float* v_ui0 = (float*)carve((size_t)NE_N * 4);
  float* v_iu0 = (float*)carve((size_t)NE_N * 4);
  unsigned short* stuBfA = (unsigned short*)carve((size_t)S_N * 128 * 2);
  unsigned short* stuBfB = (unsigned short*)carve((size_t)S_N * 128 * 2);
  unsigned short* exeBfA = (unsigned short*)carve((size_t)E_N * 128 * 2);
  unsigned short* exeBfB = (unsigned short*)carve((size_t)E_N * 128 * 2);
  float* stuS = (float*)carve((size_t)S_N * 128 * 4);
  float* exeS = (float*)carve((size_t)E_N * 128 * 4);
  int* cS = (int*)carve((size_t)S_N * 4);
  int* cE = (int*)carve((size_t)E_N * 4);
  int* rS = (int*)carve((size_t)(S_N + 1) * 4);
  int* rE = (int*)carve((size_t)(E_N + 1) * 4);
  int* qS = (int*)carve((size_t)S_N * 4);
  int* qE = (int*)carve((size_t)E_N * 4);
  int2* pairsS = (int2*)carve((size_t)2 * NE_N * 8);
  int2* pairsE = (int2*)carve((size_t)2 * NE_N * 8);
  float* xbuf = (float*)carve((size_t)B_N * 128 * 4);

  prep_kernel<<<(147584 + 255) / 256, 256, 0, stream>>>(W1_l1, W1_l0, pw1, pw2, pw3, kno_emb,
                                                        w1bf1, w1bf0, pw1T, pw2T, pw3a, keT);
  init_bf_kernel<<<(2240000 + 255) / 256, 256, 0, stream>>>(stu_emb, exe_emb, stuBfA, exeBfA,
                                                            stuS, exeS);
  zero_kernel<<<(S_N + 255) / 256, 256, 0, stream>>>(cS, S_N);
  zero_kernel<<<(E_N + 255) / 256, 256, 0, stream>>>(cE, E_N);
  hist_kernel<<<NE_N / 256, 256, 0, stream>>>(ui1_u, ui1_i, ui0_u, ui0_i, cS, cE);
  scan2_kernel<<<2, 1024, 0, stream>>>(cS, rS, qS, S_N, cE, rE, qE, E_N);
  gate_kernel<<<2048, 512, 0, stream>>>(ui1_u, ui1_i, ui1_val, iu1_val, eps_ui1, eps_iu1,
                                        stuBfA, exeBfA, w1bf1, b1_l1, W2_l1, b2_l1,
                                        v_ui1, v_iu1);
  gate_kernel<<<2048, 512, 0, stream>>>(ui0_u, ui0_i, ui0_val, iu0_val, eps_ui0, eps_iu0,
                                        stuBfA, exeBfA, w1bf0, b1_l0, W2_l0, b2_l0,
                                        v_ui0, v_iu0);
  scatter_kernel<<<NE_N / 256, 256, 0, stream>>>(ui1_u, ui1_i, ui0_u, ui0_i,
                                                 v_ui1, v_iu1, v_ui0, v_iu0,
                                                 qS, qE, pairsS, pairsE);
  const unsigned short* scur = stuBfA; const unsigned short* ecur = exeBfA;
  unsigned short* snxt = stuBfB; unsigned short* enxt = exeBfB;
  for (int layer = 0; layer < L_N; ++layer) {
    spmm_kernel<<<(S_N + E_N) / 4, 256, 0, stream>>>(rS, pairsS, rE, pairsE,
                                                     scur, ecur, snxt, enxt, stuS, exeS);
    const unsigned short* t1 = scur; scur = snxt; snxt = (unsigned short*)t1;
    const unsigned short* t2 = ecur; ecur = enxt; enxt = (unsigned short*)t2;
  }
  head1_kernel<<<B_N / 4, 256, 0, stream>>>(stu_id, exer_id, kn_emb, stuS, exeS, keT,
                                            stu_b, exe_b, disc, xbuf);
  head2_kernel<<<B_N / 4, 256, 0, stream>>>(xbuf, pw1T, pb1, pw2T, pb2, pw3a, pb3, out);
}